// Round 9
// baseline (453.330 us; speedup 1.0000x reference)
//
#include <hip/hip_runtime.h>

// ---------------------------------------------------------------------------
// Fused TransformerBlock: x += MSA(LN(x)) twice, then x += MLP(LN(x)).
// B=4 T=1024 C=1024 H=16 hd=64. fp32 residuals, bf16 GEMM/MFMA inputs.
// Round-9: QKV + MLP1 GEMMs -> 256x256 8-phase schedule (T2+T3+T4+T5):
// BK=64 in two K-halves, 8 waves (2Mx4N), 128KB LDS dbuf, counted vmcnt(4)
// (never 0 in-loop), raw s_barrier, setprio around MFMA clusters.
// MLP2 stays on the proven 128^2 2-phase split-K path.
// ---------------------------------------------------------------------------

#define DEVI __device__ __forceinline__

typedef unsigned short u16;
typedef short bf16x8 __attribute__((ext_vector_type(8)));   // 8 bf16 = 4 VGPR
typedef float f32x4 __attribute__((ext_vector_type(4)));
typedef unsigned short u16x4 __attribute__((ext_vector_type(4)));

DEVI u16 f2bf(float f) {                 // RNE fp32 -> bf16
  union { float f; unsigned u; } v; v.f = f;
  unsigned r = v.u + 0x7FFFu + ((v.u >> 16) & 1u);
  return (u16)(r >> 16);
}
DEVI float bf2f(u16 u) {
  union { unsigned u; float f; } v; v.u = ((unsigned)u) << 16; return v.f;
}

DEVI void gload16(const void* g, void* l) {   // async global->LDS, 16B/lane
  __builtin_amdgcn_global_load_lds((const __attribute__((address_space(1))) void*)g,
                                   (__attribute__((address_space(3))) void*)l,
                                   16, 0, 0);
}

// ---------------------------------------------------------------------------
// Weight packs (fp32 -> bf16, transposed to Bt[N][K] layout for the GEMM)
// ---------------------------------------------------------------------------

// W [16][1024][64] fp32  ->  out rows [h*64+d][1024] bf16
__global__ __launch_bounds__(256) void k_pack_headw(const float* __restrict__ W,
                                                    u16* __restrict__ out) {
  const int k0 = blockIdx.x * 64;
  const int h  = blockIdx.y;
  __shared__ float t[64][65];
  const int tid = threadIdx.x;
#pragma unroll
  for (int p = 0; p < 16; p++) {
    int e = p * 256 + tid, kk = e >> 6, d = e & 63;
    t[kk][d] = W[h * 65536 + (k0 + kk) * 64 + d];
  }
  __syncthreads();
#pragma unroll
  for (int p = 0; p < 16; p++) {
    int e = p * 256 + tid, d = e >> 6, kk = e & 63;
    out[(size_t)(h * 64 + d) * 1024 + k0 + kk] = f2bf(t[kk][d]);
  }
}

// in [R][C] fp32 -> out [C][R] bf16
__global__ __launch_bounds__(256) void k_transpose(const float* __restrict__ in,
                                                   u16* __restrict__ out,
                                                   int R, int C) {
  const int c0 = blockIdx.x * 64, r0 = blockIdx.y * 64;
  __shared__ float t[64][65];
  const int tid = threadIdx.x;
#pragma unroll
  for (int p = 0; p < 16; p++) {
    int e = p * 256 + tid, rr = e >> 6, cc = e & 63;
    t[rr][cc] = in[(size_t)(r0 + rr) * C + c0 + cc];
  }
  __syncthreads();
#pragma unroll
  for (int p = 0; p < 16; p++) {
    int e = p * 256 + tid, cc = e >> 6, rr = e & 63;
    out[(size_t)(c0 + cc) * R + r0 + rr] = f2bf(t[rr][cc]);
  }
}

// ---------------------------------------------------------------------------
// LayerNorm (+ optional bf16 residual add)
// ---------------------------------------------------------------------------
__global__ __launch_bounds__(256) void k_ln(const float* __restrict__ xin,
                                            const u16* __restrict__ oin,
                                            float* __restrict__ xsum,
                                            u16* __restrict__ xn,
                                            const float* __restrict__ g,
                                            const float* __restrict__ b) {
  const int row = blockIdx.x;
  const size_t base = (size_t)row * 1024;
  const int tid = threadIdx.x;
  float4 xv = ((const float4*)(xin + base))[tid];
  if (oin) {
    u16x4 ov = *(const u16x4*)(oin + base + tid * 4);
    xv.x += bf2f(ov[0]); xv.y += bf2f(ov[1]);
    xv.z += bf2f(ov[2]); xv.w += bf2f(ov[3]);
  }
  if (xsum) ((float4*)(xsum + base))[tid] = xv;
  float s = xv.x + xv.y + xv.z + xv.w;
  float q = xv.x * xv.x + xv.y * xv.y + xv.z * xv.z + xv.w * xv.w;
#pragma unroll
  for (int m = 1; m < 64; m <<= 1) { s += __shfl_xor(s, m); q += __shfl_xor(q, m); }
  __shared__ float red[8];
  const int wave = tid >> 6, lane = tid & 63;
  if (lane == 0) { red[wave] = s; red[4 + wave] = q; }
  __syncthreads();
  s = red[0] + red[1] + red[2] + red[3];
  q = red[4] + red[5] + red[6] + red[7];
  const float mean = s * (1.f / 1024.f);
  const float var  = q * (1.f / 1024.f) - mean * mean;
  const float rstd = rsqrtf(var + 1e-5f);
  float4 gv = ((const float4*)g)[tid];
  float4 bv = ((const float4*)b)[tid];
  u16x4 o;
  o[0] = f2bf((xv.x - mean) * rstd * gv.x + bv.x);
  o[1] = f2bf((xv.y - mean) * rstd * gv.y + bv.y);
  o[2] = f2bf((xv.z - mean) * rstd * gv.z + bv.z);
  o[3] = f2bf((xv.w - mean) * rstd * gv.w + bv.w);
  *(u16x4*)(xn + base + tid * 4) = o;
}

// ---------------------------------------------------------------------------
// 256x256 8-phase GEMM (T2+T3+T4+T5). C = A[M,K] * Bt[N,K]^T, bf16->fp32.
// 8 waves (wm 0..1 x wn 0..3), per-wave out 128x64 (8x4 frags). BK=64 as two
// K-halves of 32. LDS 128KB: [dbuf][A/B][ks][256 rows][32 bf16], chunk-XOR
// swizzled (slot q holds global cols q^(row&3); readers apply same XOR).
// Per tile t: 4 phases (ks,fh); each stages one half-tile of t+1 (2 gloads/
// thread). vmcnt(4) at ends of ph1/ph3 gates exactly the data the next two
// phases read (counted, never 0). Raw s_barrier x2/phase; setprio on MFMA.
// EPI 0: bf16 store. 1: +bias relu bf16.
// ---------------------------------------------------------------------------
#define BAR() __builtin_amdgcn_s_barrier()
#define VMW4() asm volatile("s_waitcnt vmcnt(4)" ::: "memory")

template <int EPI>
__global__ __launch_bounds__(512, 2) void gemm256(const u16* __restrict__ A,
                                                  const u16* __restrict__ Bt,
                                                  void* __restrict__ outp,
                                                  const float* __restrict__ bias,
                                                  int M, int N, int K) {
  __shared__ u16 LS[65536];                 // 128 KiB
  const int tid = threadIdx.x;
  const int wave = tid >> 6, lane = tid & 63;
  const int lg = lane >> 4, l15 = lane & 15;
  const int wm = wave >> 2, wn = wave & 3;

  // T1 XCD-chunked swizzle (nwg % 8 == 0 in all launches)
  const int gx = gridDim.x, nwg = gx * gridDim.y;
  int bid = blockIdx.y * gx + blockIdx.x;
  bid = (bid & 7) * (nwg >> 3) + (bid >> 3);
  const int by = bid / gx, bx = bid % gx;

  const u16* Ab = A + (size_t)by * 256 * K;
  const u16* Bb = Bt + (size_t)bx * 256 * K;

  // staging: chunk c=tid -> row c>>2 (0..127), slot c&3; c=512+tid -> row+128.
  const int r0 = tid >> 2, r1 = r0 + 128, sq = tid & 3;
  const int q0s = (sq ^ (r0 & 3)) * 8;      // swizzled source col (u16)
  const int q1s = (sq ^ (r1 & 3)) * 8;
  // LDS u16 offsets: dbuf*32768 + (A:0|B:16384) + ks*8192 + chunk*8
  const int wbase = wave * 512;             // wave-uniform dest base (chunks)

#define STG(buf, abo, ks, Xb, tk)                                              \
  {                                                                            \
    u16* dst = &LS[(buf) * 32768 + (abo) + (ks) * 8192 + wbase];               \
    gload16((Xb) + (size_t)r0 * K + (tk) + (ks) * 32 + q0s, dst);              \
    gload16((Xb) + (size_t)r1 * K + (tk) + (ks) * 32 + q1s, dst + 4096);       \
  }

  // reader offsets
  const int aswz = (lg ^ (l15 & 3)) << 3;   // u16 within 32-u16 row
  const int rowA = wm * 128 + l15;
  const int rowB = wn * 64 + l15;

  f32x4 acc[8][4];
  const f32x4 zero = {0.f, 0.f, 0.f, 0.f};
#pragma unroll
  for (int i = 0; i < 8; i++)
#pragma unroll
    for (int j = 0; j < 4; j++) acc[i][j] = zero;

  bf16x8 af[4], bf[4];

#define RD_B(cur, ks)                                                          \
  _Pragma("unroll") for (int j = 0; j < 4; j++)                                \
      bf[j] = *(const bf16x8*)&LS[(cur) * 32768 + 16384 + (ks) * 8192 +        \
                                  (rowB + j * 16) * 32 + aswz];
#define RD_A(cur, ks, fh)                                                      \
  _Pragma("unroll") for (int i = 0; i < 4; i++)                                \
      af[i] = *(const bf16x8*)&LS[(cur) * 32768 + (ks) * 8192 +                \
                                  (rowA + ((fh) * 4 + i) * 16) * 32 + aswz];
#define MFMA16(fh)                                                             \
  __builtin_amdgcn_s_setprio(1);                                               \
  _Pragma("unroll") for (int i = 0; i < 4; i++)                                \
      _Pragma("unroll") for (int j = 0; j < 4; j++)                            \
          acc[(fh) * 4 + i][j] = __builtin_amdgcn_mfma_f32_16x16x32_bf16(      \
              af[i], bf[j], acc[(fh) * 4 + i][j], 0, 0, 0);                    \
  __builtin_amdgcn_s_setprio(0);

  const int NT = K >> 6;                    // 64-wide K tiles (16 for K=1024)

  // prologue: stage all 4 half-tiles of tile 0 into buf 0
  STG(0, 0,     0, Ab, 0);                  // AK0
  STG(0, 16384, 0, Bb, 0);                  // BK0
  STG(0, 0,     1, Ab, 0);                  // AK1
  STG(0, 16384, 1, Bb, 0);                  // BK1
  VMW4();                                   // AK0,BK0 landed (AK1,BK1 may fly)
  BAR();

  for (int t = 0; t < NT; ++t) {
    const int cur = t & 1, nxt = cur ^ 1;
    const int tk = (t + 1) << 6;
    const bool st = (t + 1 < NT);
    // ---- ph0: (ks0, fh0) ----
    RD_B(cur, 0); RD_A(cur, 0, 0);
    if (st) STG(nxt, 0, 0, Ab, tk);         // AK0(t+1)
    BAR();
    MFMA16(0);
    BAR();
    // ---- ph1: (ks0, fh1) ----
    RD_A(cur, 0, 1);
    if (st) STG(nxt, 16384, 0, Bb, tk);     // BK0(t+1)
    BAR();
    MFMA16(1);
    VMW4();                                 // gate AK1(t),BK1(t)
    BAR();
    // ---- ph2: (ks1, fh0) ----
    RD_B(cur, 1); RD_A(cur, 1, 0);
    if (st) STG(nxt, 0, 1, Ab, tk);         // AK1(t+1)
    BAR();
    MFMA16(0);
    BAR();
    // ---- ph3: (ks1, fh1) ----
    RD_A(cur, 1, 1);
    if (st) STG(nxt, 16384, 1, Bb, tk);     // BK1(t+1)
    BAR();
    MFMA16(1);
    VMW4();                                 // gate AK0(t+1),BK0(t+1)
    BAR();
  }
#undef STG
#undef RD_A
#undef RD_B
#undef MFMA16

  // C/D layout: col = lane&15, row = (lane>>4)*4 + reg  [m89/m91 verified]
  const int rb = by * 256 + wm * 128 + lg * 4;
  const int cb = bx * 256 + wn * 64 + l15;
  if constexpr (EPI == 0) {
    u16* out = (u16*)outp;
#pragma unroll
    for (int i8 = 0; i8 < 8; i8++)
#pragma unroll
      for (int j = 0; j < 4; j++)
#pragma unroll
        for (int r = 0; r < 4; r++)
          out[(size_t)(rb + i8 * 16 + r) * N + cb + j * 16] = f2bf(acc[i8][j][r]);
  } else {
    u16* out = (u16*)outp;
#pragma unroll
    for (int j = 0; j < 4; j++) {
      const float bv = bias[cb + j * 16];
#pragma unroll
      for (int i8 = 0; i8 < 8; i8++)
#pragma unroll
        for (int r = 0; r < 4; r++)
          out[(size_t)(rb + i8 * 16 + r) * N + cb + j * 16] =
              f2bf(fmaxf(acc[i8][j][r] + bv, 0.f));
    }
  }
}

// ---------------------------------------------------------------------------
// 128x128 2-phase GEMM (kept for MLP2 split-K): EPI 3 = fp32 partial.
// ---------------------------------------------------------------------------
template <int EPI>
__global__ __launch_bounds__(256, 4) void gemm_bt(const u16* __restrict__ A,
                                                  const u16* __restrict__ Bt,
                                                  void* __restrict__ outp,
                                                  void* __restrict__ outp2,
                                                  const float* __restrict__ bias,
                                                  int M, int N, int K) {
  __shared__ u16 As[2][128 * 32];
  __shared__ u16 Bs[2][128 * 32];
  const int tid = threadIdx.x;
  const int wave = tid >> 6, lane = tid & 63;
  const int lg = lane >> 4, l15 = lane & 15;
  const int wr = wave >> 1, wc = wave & 1;

  const int nwg = gridDim.x * gridDim.y;
  int bid = blockIdx.y * gridDim.x + blockIdx.x;
  bid = (bid & 7) * (nwg >> 3) + (bid >> 3);
  const int by = bid / gridDim.x, bx = bid % gridDim.x;

  const int Ksz   = (EPI == 3) ? (K >> 1) : K;
  const int kbase = (EPI == 3) ? (int)blockIdx.z * Ksz : 0;

  const u16* Ab = A + (size_t)by * 128 * K;
  const u16* Bb = Bt + (size_t)bx * 128 * K;

  const int r0 = tid >> 2, q = tid & 3, r1 = r0 + 64;
  const int c0s = (q ^ ((r0 >> 1) & 3)) * 8;
  const int c1s = (q ^ ((r1 >> 1) & 3)) * 8;
  char* const a0[2] = {(char*)As[0] + wave * 1024, (char*)As[1] + wave * 1024};
  char* const a1[2] = {(char*)As[0] + 4096 + wave * 1024, (char*)As[1] + 4096 + wave * 1024};
  char* const b0[2] = {(char*)Bs[0] + wave * 1024, (char*)Bs[1] + wave * 1024};
  char* const b1[2] = {(char*)Bs[0] + 4096 + wave * 1024, (char*)Bs[1] + 4096 + wave * 1024};

#define STAGE(b, kk)                                       \
  gload16(Ab + (size_t)r0 * K + (kk) + c0s, a0[b]);        \
  gload16(Ab + (size_t)r1 * K + (kk) + c1s, a1[b]);        \
  gload16(Bb + (size_t)r0 * K + (kk) + c0s, b0[b]);        \
  gload16(Bb + (size_t)r1 * K + (kk) + c1s, b1[b]);

  int aoff[4], boff[4];
#pragma unroll
  for (int i = 0; i < 4; i++) {
    int Ra = wr * 64 + i * 16 + l15;
    aoff[i] = Ra * 64 + ((lg ^ ((Ra >> 1) & 3)) << 4);
    int Rb = wc * 64 + i * 16 + l15;
    boff[i] = Rb * 64 + ((lg ^ ((Rb >> 1) & 3)) << 4);
  }

  const f32x4 zero = {0.f, 0.f, 0.f, 0.f};
  f32x4 acc[4][4];
#pragma unroll
  for (int i = 0; i < 4; i++)
#pragma unroll
    for (int j = 0; j < 4; j++) acc[i][j] = zero;

#define COMPUTE(b)                                                             \
  {                                                                            \
    bf16x8 af[4], bfv[4];                                                      \
    _Pragma("unroll") for (int i = 0; i < 4; i++)                              \
        af[i] = *(const bf16x8*)((const char*)As[b] + aoff[i]);                \
    _Pragma("unroll") for (int j = 0; j < 4; j++)                              \
        bfv[j] = *(const bf16x8*)((const char*)Bs[b] + boff[j]);               \
    _Pragma("unroll") for (int i = 0; i < 4; i++)                              \
        _Pragma("unroll") for (int j = 0; j < 4; j++)                          \
            acc[i][j] = __builtin_amdgcn_mfma_f32_16x16x32_bf16(               \
                af[i], bfv[j], acc[i][j], 0, 0, 0);                            \
  }

  const int NT = Ksz >> 5;
  STAGE(0, kbase);
  __syncthreads();
  for (int t = 0; t < NT; t += 2) {
    STAGE(1, kbase + (t + 1) * 32);
    COMPUTE(0);
    __syncthreads();
    if (t + 2 < NT) { STAGE(0, kbase + (t + 2) * 32); }
    COMPUTE(1);
    __syncthreads();
  }
#undef STAGE
#undef COMPUTE

  const int rbase = by * 128 + wr * 64 + lg * 4;
  const int cbase = bx * 128 + wc * 64 + l15;
  if constexpr (EPI == 3) {
    float* out = blockIdx.z ? (float*)outp2 : (float*)outp;
#pragma unroll
    for (int i = 0; i < 4; i++)
#pragma unroll
      for (int j = 0; j < 4; j++)
#pragma unroll
        for (int r = 0; r < 4; r++)
          out[(size_t)(rbase + i * 16 + r) * N + cbase + j * 16] = acc[i][j][r];
  } else {
    u16* out = (u16*)outp;
#pragma unroll
    for (int i = 0; i < 4; i++)
#pragma unroll
      for (int j = 0; j < 4; j++)
#pragma unroll
        for (int r = 0; r < 4; r++)
          out[(size_t)(rbase + i * 16 + r) * N + cbase + j * 16] = f2bf(acc[i][j][r]);
  }
  (void)bias;
}

// combine split-K partials: xacc += P0 + P1 + bias
__global__ __launch_bounds__(256) void k_comb(const float* __restrict__ P0,
                                              const float* __restrict__ P1,
                                              const float* __restrict__ bias,
                                              float* __restrict__ xacc) {
  const size_t i = (size_t)blockIdx.x * 1024 + threadIdx.x * 4;
  float4 a = *(const float4*)(P0 + i);
  float4 b = *(const float4*)(P1 + i);
  float4 x = *(const float4*)(xacc + i);
  float4 bv = *(const float4*)(bias + threadIdx.x * 4);
  x.x += a.x + b.x + bv.x;
  x.y += a.y + b.y + bv.y;
  x.z += a.z + b.z + bv.z;
  x.w += a.w + b.w + bv.w;
  *(float4*)(xacc + i) = x;
}

// ---------------------------------------------------------------------------
// K/V fragment pack (unchanged)
// ---------------------------------------------------------------------------
__global__ __launch_bounds__(256) void k_packkv(const u16* __restrict__ QKV,
                                                u16* __restrict__ Kp,
                                                u16* __restrict__ Vp) {
  const int t  = blockIdx.x;
  const int bh = blockIdx.y, b = bh >> 4, h = bh & 15;
  const int tid = threadIdx.x;
  __shared__ u16 vt[64][80];

  const u16* Ksrc = QKV + (size_t)(b * 1024 + t * 64) * 3072 + 1024 + h * 64;
  const u16* Vsrc = QKV + (size_t)(b * 1024 + t * 64) * 3072 + 2048 + h * 64;
  u16* KpT = Kp + (size_t)(bh * 16 + t) * 4096;
  u16* VpT = Vp + (size_t)(bh * 16 + t) * 4096;

#pragma unroll
  for (int p = 0; p < 2; p++) {
    int e = p * 256 + tid, rr = e >> 3, dd = (e & 7) * 8;
    *(bf16x8*)&vt[rr][dd] = *(const bf16x8*)(Ksrc + (size_t)rr * 3072 + dd);
  }
  __syncthreads();
#pragma unroll
  for (int p = 0; p < 2; p++) {
    int c = p * 256 + tid;
    int i = c >> 6, lane = c & 63, lgg = lane >> 4, ll = lane & 15;
    int j = i >> 1;
    int row = 8 * (ll >> 2) + (ll & 3) + (j & 1) * 4 + (j >> 1) * 32;
    int col = (i & 1) * 32 + lgg * 8;
    *(bf16x8*)&KpT[(size_t)c * 8] = *(const bf16x8*)&vt[row][col];
  }
  __syncthreads();
#pragma unroll
  for (int p = 0; p < 2; p++) {
    int e = p * 256 + tid, rr = e >> 3, dd = (e & 7) * 8;
    *(bf16x8*)&vt[rr][dd] = *(const bf16x8*)(Vsrc + (size_t)rr * 3072 + dd);
  }
  __syncthreads();
#pragma unroll
  for (int p = 0; p < 2; p++) {
    int c = p * 256 + tid;
    int i = c >> 6, lane = c & 63, lgg = lane >> 4, ll = lane & 15;
    int dg = (i >> 1) & 3, kh = i & 1;
    bf16x8 o;
#pragma unroll
    for (int jj = 0; jj < 8; jj++)
      o[jj] = (short)vt[kh * 32 + lgg * 8 + jj][dg * 16 + ll];
    *(bf16x8*)&VpT[(size_t)c * 8] = o;
  }
}

// ---------------------------------------------------------------------------
// Flash attention fwd (unchanged from round 8)
// ---------------------------------------------------------------------------
DEVI void load8(bf16x8 (&r)[8], const u16* p) {
#pragma unroll
  for (int i = 0; i < 8; i++) r[i] = *(const bf16x8*)(p + i * 512);
}

DEVI void attn_tile32(const bf16x8 (&kr)[8], const bf16x8 (&vr)[8],
                      const bf16x8 (&qf)[2][2], f32x4 (&oa)[2][4],
                      float (&m)[2], float (&sden)[2], int lg, float cexp) {
  const f32x4 zero = {0.f, 0.f, 0.f, 0.f};
#pragma unroll
  for (int qh = 0; qh < 2; qh++) {
    f32x4 s0 = zero, s1 = zero, s2 = zero, s3 = zero;
    s0 = __builtin_amdgcn_mfma_f32_16x16x32_bf16(kr[0], qf[qh][0], s0, 0, 0, 0);
    s0 = __builtin_amdgcn_mfma_f32_16x16x32_bf16(kr[1], qf[qh][1], s0, 0, 0, 0);
    s1 = __builtin_amdgcn_mfma_f32_16x16x32_bf16(kr[2], qf[qh][0], s1, 0, 0, 0);
    s1 = __builtin_amdgcn_mfma_f32_16x16x32_bf16(kr[3], qf[qh][1], s1, 0, 0, 0);
    s2 = __builtin_amdgcn_mfma_f32_16x16x32_bf16(kr[4], qf[qh][0], s2, 0, 0, 0);
    s2 = __builtin_amdgcn_mfma_f32_16x16x32_bf16(kr[5], qf[qh][1], s2, 0, 0, 0);
    s3 = __builtin_amdgcn_mfma_f32_16x16x32_bf16(kr[6], qf[qh][0], s3, 0, 0, 0);
    s3 = __builtin_amdgcn_mfma_f32_16x16x32_bf16(kr[7], qf[qh][1], s3, 0, 0, 0);

    f32x4 mv = s0;
#pragma unroll
    for (int r = 0; r < 4; r++) mv[r] = fmaxf(fmaxf(mv[r], s1[r]), fmaxf(s2[r], s3[r]));
    float mx = fmaxf(fmaxf(mv[0], mv[1]), fmaxf(mv[2], mv[3]));
    mx = fmaxf(mx, __shfl_xor(mx, 16));
    mx = fmaxf(mx, __shfl_xor(mx, 32));
    const float mn = fmaxf(m[qh], mx);
    const float fr = exp2f((m[qh] - mn) * cexp);
    m[qh] = mn;
#pragma unroll
    for (int r = 0; r < 4; r++) {
      s0[r] = exp2f((s0[r] - mn) * cexp);
      s1[r] = exp2f((s1[r] - mn) * cexp);
      s2[r] = exp2f((s2[r] - mn) * cexp);
      s3[r] = exp2f((s3[r] - mn) * cexp);
    }
    f32x4 sv = (s0 + s1) + (s2 + s3);
    float ts = (sv[0] + sv[1]) + (sv[2] + sv[3]);
    ts += __shfl_xor(ts, 16);
    ts += __shfl_xor(ts, 32);
    sden[qh] = sden[qh] * fr + ts;

    bf16x8 pa0, pa1;
#pragma unroll
    for (int r = 0; r < 4; r++) {
      pa0[r]     = (short)f2bf(s0[r]);
      pa0[4 + r] = (short)f2bf(s1[r]);
      pa1[r]     = (short)f2bf(s2[r]);
      pa1[4 + r] = (short)f2bf(s3[r]);
    }

    float frq[4];
#pragma unroll
    for (int r = 0; r < 4; r++) frq[r] = __shfl(fr, 20 * lg + r, 64);
#pragma unroll
    for (int dg = 0; dg < 4; dg++) {
      oa[qh][dg][0] *= frq[0]; oa[qh][dg][1] *= frq[1];
      oa[qh][dg][2] *= frq[2]; oa[qh][dg][3] *= frq[3];
      oa[qh][dg] = __builtin_amdgcn_mfma_f32_16x16x32_bf16(pa0, vr[2 * dg],     oa[qh][dg], 0, 0, 0);
      oa[qh][dg] = __builtin_amdgcn_mfma_f32_16x16x32_bf16(pa1, vr[2 * dg + 1], oa[qh][dg], 0, 0, 0);
    }
  }
}

__global__ __launch_bounds__(256) void k_attn(const u16* __restrict__ QKV,
                                              const u16* __restrict__ Kp,
                                              const u16* __restrict__ Vp,
                                              u16* __restrict__ O) {
  const int Tn = 1024;
  const int bh = blockIdx.x, b = bh >> 4, h = bh & 15;
  const int q0 = blockIdx.y * 128;
  const int tid = threadIdx.x, wave = tid >> 6, lane = tid & 63;
  const int lg = lane >> 4, l15 = lane & 15;

  const u16* Qb = QKV + (size_t)(b * Tn + q0 + wave * 32 + l15) * 3072 + h * 64 + lg * 8;
  bf16x8 qf[2][2];
  qf[0][0] = *(const bf16x8*)Qb;
  qf[0][1] = *(const bf16x8*)(Qb + 32);
  qf[1][0] = *(const bf16x8*)(Qb + 16 * 3072);
  qf[1][1] = *(const bf16x8*)(Qb + 16 * 3072 + 32);

  const u16* KpB = Kp + (size_t)bh * 65536 + lane * 8;
  const u16* VpB = Vp + (size_t)bh * 65536 + lane * 8;

  const float cexp = 0.03125f * 1.44269504f;

  float m[2] = {-1e30f, -1e30f}, sden[2] = {0.f, 0.f};
  const f32x4 zero = {0.f, 0.f, 0.f, 0.f};
  f32x4 oa[2][4];
#pragma unroll
  for (int qh = 0; qh < 2; qh++)
#pragma unroll
    for (int dg = 0; dg < 4; dg++) oa[qh][dg] = zero;

  bf16x8 ka[8], va[8], kb[8], vb[8];
  load8(ka, KpB);
  load8(va, VpB);

  for (int t = 0; t < 16; t += 2) {
    load8(kb, KpB + (t + 1) * 4096);
    load8(vb, VpB + (t + 1) * 4096);
    attn_tile32(ka, va, qf, oa, m, sden, lg, cexp);
    if (t + 2 < 16) {
      load8(ka, KpB + (t + 2) * 4096);
      load8(va, VpB + (t + 2) * 4096);
    }
    attn_tile32(kb, vb, qf, oa, m, sden, lg, cexp);
  }

#pragma unroll
  for (int qh = 0; qh < 2; qh++) {
    float sdq[4];
#pragma unroll
    for (int r = 0; r < 4; r++) sdq[r] = 1.f / __shfl(sden[qh], 20 * lg + r, 64);
    u16* Ob = O + (size_t)(b * Tn + q0 + wave * 32 + qh * 16) * 1024 + h * 64;
#pragma unroll
    for (int dg = 0; dg < 4; dg++)
#pragma unroll
      for (int r = 0; r < 4; r++)
        Ob[(size_t)(lg * 4 + r) * 1024 + dg * 16 + l15] = f2bf(oa[qh][dg][r] * sdq[r]);
  }
}

// ---------------------------------------------------------------------------
// Launch
// ---------------------------------------------------------------------------
extern "C" void kernel_launch(void* const* d_in, const int* in_sizes, int n_in,
                              void* d_out, int out_size, void* d_ws, size_t ws_size,
                              hipStream_t stream) {
  const float* x   = (const float*)d_in[0];
  const float* Wq1 = (const float*)d_in[1];
  const float* Wk1 = (const float*)d_in[2];
  const float* Wv1 = (const float*)d_in[3];
  const float* Wq2 = (const float*)d_in[4];
  const float* Wk2 = (const float*)d_in[5];
  const float* Wv2 = (const float*)d_in[6];
  const float* g1  = (const float*)d_in[7];
  const float* b1  = (const float*)d_in[8];
  const float* g2  = (const float*)d_in[9];
  const float* b2  = (const float*)d_in[10];
  const float* g3  = (const float*)d_in[11];
  const float* b3  = (const float*)d_in[12];
  const float* W1  = (const float*)d_in[13];
  const float* bf1 = (const float*)d_in[14];
  const float* W2  = (const float*)d_in[15];
  const float* bf2 = (const float*)d_in[16];

  char* ws = (char*)d_ws;
  u16* Wqkv1t = (u16*)(ws);                    //  6,291,456  [3072][1024]
  u16* Wqkv2t = (u16*)(ws + 6291456);          //  6,291,456
  u16* W1t    = (u16*)(ws + 12582912);         //  8,388,608  [4096][1024]
  u16* W2t    = (u16*)(ws + 20971520);         //  8,388,608  [1024][4096]
  u16* xn     = (u16*)(ws + 29360128);         //  8,388,608  [4096][1024]
  u16* QKV    = (u16*)(ws + 37748736);         // 25,165,824  [4096][3072]
  u16* Kp     = (u16*)(ws + 62914560);         //  8,388,608  frag-packed K
  u16* Vp     = (u16*)(ws + 71303168);         //  8,388,608  frag-packed V
  u16* O      = (u16*)(ws + 79691776);         //  8,388,608  attn out (bf16)
  u16* h1     = (u16*)(ws + 37748736);         // 33,554,432  aliases QKV+Kp (dead by MLP)
  float* P0   = (float*)(ws);                  // 16,777,216  over Wqkv*/W1t (dead)
  float* P1   = (float*)(ws + 71303168);       // 16,777,216  over Vp+O (dead)
  float* xacc = (float*)d_out;                 // fp32 running residual in d_out

  const dim3 blk(256);
  const dim3 blk5(512);

  // weight packs
  k_pack_headw<<<dim3(16, 16), blk, 0, stream>>>(Wq1, Wqkv1t);
  k_pack_headw<<<dim3(16, 16), blk, 0, stream>>>(Wk1, Wqkv1t + 1024 * 1024);
  k_pack_headw<<<dim3(16, 16), blk, 0, stream>>>(Wv1, Wqkv1t + 2048 * 1024);
  k_pack_headw<<<dim3(16, 16), blk, 0, stream>>>(Wq2, Wqkv2t);
  k_pack_headw<<<dim3(16, 16), blk, 0, stream>>>(Wk2, Wqkv2t + 1024 * 1024);
  k_pack_headw<<<dim3(16, 16), blk, 0, stream>>>(Wv2, Wqkv2t + 2048 * 1024);
  k_transpose<<<dim3(64, 16), blk, 0, stream>>>(W1, W1t, 1024, 4096);
  k_transpose<<<dim3(16, 64), blk, 0, stream>>>(W2, W2t, 4096, 1024);

  // ---- layer 1 MSA ----
  k_ln<<<4096, blk, 0, stream>>>(x, nullptr, nullptr, xn, g1, b1);
  gemm256<0><<<dim3(12, 16), blk5, 0, stream>>>(xn, Wqkv1t, QKV, nullptr, 4096, 3072, 1024);
  k_packkv<<<dim3(16, 64), blk, 0, stream>>>(QKV, Kp, Vp);
  k_attn<<<dim3(64, 8), blk, 0, stream>>>(QKV, Kp, Vp, O);
  k_ln<<<4096, blk, 0, stream>>>(x, O, xacc, xn, g2, b2);

  // ---- layer 2 MSA ----
  gemm256<0><<<dim3(12, 16), blk5, 0, stream>>>(xn, Wqkv2t, QKV, nullptr, 4096, 3072, 1024);
  k_packkv<<<dim3(16, 64), blk, 0, stream>>>(QKV, Kp, Vp);
  k_attn<<<dim3(64, 8), blk, 0, stream>>>(QKV, Kp, Vp, O);
  k_ln<<<4096, blk, 0, stream>>>(xacc, O, xacc, xn, g3, b3);

  // ---- MLP ----
  gemm256<1><<<dim3(16, 16), blk5, 0, stream>>>(xn, W1t, h1, bf1, 4096, 4096, 1024);
  gemm_bt<3><<<dim3(8, 32, 2), blk, 0, stream>>>(h1, W2t, P0, P1, nullptr, 4096, 1024, 4096);
  k_comb<<<4096, blk, 0, stream>>>(P0, P1, bf2, xacc);

  (void)in_sizes; (void)n_in; (void)out_size; (void)ws_size;
}